// Round 1
// baseline (124.187 us; speedup 1.0000x reference)
//
#include <hip/hip_runtime.h>

// ChamferLoss: B=4, N=M=8192, D=3, fp32 in/out (scalar).
// loss = mean_b[ mean(pred2gt) + mean(gt2pred) + max(pred2gt) ]
// Compute-bound VALU fp32: 537M pairs x 5 ops (add + 3 fma + min) via
// d = ||x||^2 + ||y||^2 - 2 x.y with y pre-transformed to (-2y, ||y||^2) in LDS.

#define BATCH   4
#define NPTS    8192
#define SLICES  16
#define MS      (NPTS / SLICES)     // 512 y-points per slice
#define PPT     8                   // points per thread (register tile)
#define TPB     256
#define CHUNK   (TPB * PPT)         // 2048 points per block
#define NCHUNKS (NPTS / CHUNK)      // 4

__global__ __launch_bounds__(TPB)
void nn_partial(const float* __restrict__ pred,
                const float* __restrict__ gt,
                float* __restrict__ pmin) {
    const int c  = blockIdx.x;       // point chunk
    const int s  = blockIdx.y;       // y slice
    const int bd = blockIdx.z;       // b*2 + dir
    const int b  = bd >> 1;
    const int dir = bd & 1;
    const float* x = (dir ? gt : pred) + (size_t)b * NPTS * 3;
    const float* y = (dir ? pred : gt) + (size_t)b * NPTS * 3;

    __shared__ float4 ys[MS];        // {-2yx, -2yy, -2yz, y2}
    const int t = threadIdx.x;
    for (int j = t; j < MS; j += TPB) {
        const float yx = y[(s * MS + j) * 3 + 0];
        const float yy = y[(s * MS + j) * 3 + 1];
        const float yz = y[(s * MS + j) * 3 + 2];
        ys[j] = make_float4(-2.f * yx, -2.f * yy, -2.f * yz,
                            yx * yx + yy * yy + yz * yz);
    }
    __syncthreads();

    float xx[PPT], xy[PPT], xz[PPT], x2[PPT], mn[PPT];
    #pragma unroll
    for (int k = 0; k < PPT; ++k) {
        const int p = c * CHUNK + k * TPB + t;
        xx[k] = x[p * 3 + 0];
        xy[k] = x[p * 3 + 1];
        xz[k] = x[p * 3 + 2];
        x2[k] = xx[k] * xx[k] + xy[k] * xy[k] + xz[k] * xz[k];
        mn[k] = 3.4e38f;
    }

    #pragma unroll 2
    for (int j = 0; j < MS; ++j) {
        const float4 q = ys[j];      // uniform address -> LDS broadcast
        #pragma unroll
        for (int k = 0; k < PPT; ++k) {
            float d = x2[k] + q.w;
            d = fmaf(xz[k], q.z, d);
            d = fmaf(xy[k], q.y, d);
            d = fmaf(xx[k], q.x, d);
            mn[k] = fminf(mn[k], d);
        }
    }

    float* o = pmin + ((size_t)bd * SLICES + s) * NPTS + c * CHUNK;
    #pragma unroll
    for (int k = 0; k < PPT; ++k) o[k * TPB + t] = mn[k];
}

// One block per (b,dir): min over SLICES partials, then sum+max across points.
__global__ __launch_bounds__(256)
void reduce_bd(const float* __restrict__ pmin, float* __restrict__ partials) {
    const int bd = blockIdx.x;
    const int t  = threadIdx.x;
    const float* base = pmin + (size_t)bd * SLICES * NPTS;
    float sum = 0.f, mx = -1.f;
    for (int p = t; p < NPTS; p += 256) {
        float m = 3.4e38f;
        #pragma unroll
        for (int s = 0; s < SLICES; ++s) m = fminf(m, base[s * NPTS + p]);
        sum += m;
        mx = fmaxf(mx, m);
    }
    __shared__ float ssum[4], smax[4];
    #pragma unroll
    for (int off = 32; off; off >>= 1) {
        sum += __shfl_down(sum, off, 64);
        mx = fmaxf(mx, __shfl_down(mx, off, 64));
    }
    const int w = t >> 6;
    if ((t & 63) == 0) { ssum[w] = sum; smax[w] = mx; }
    __syncthreads();
    if (t == 0) {
        const float S = ssum[0] + ssum[1] + ssum[2] + ssum[3];
        const float M = fmaxf(fmaxf(smax[0], smax[1]), fmaxf(smax[2], smax[3]));
        partials[bd * 2]     = S;
        partials[bd * 2 + 1] = M;
    }
}

__global__ void finalize(const float* __restrict__ partials,
                         float* __restrict__ out) {
    float acc = 0.f;
    #pragma unroll
    for (int b = 0; b < BATCH; ++b) {
        const float s_p2g = partials[(b * 2 + 0) * 2];      // pred2gt sum
        const float m_p2g = partials[(b * 2 + 0) * 2 + 1];  // pred2gt max
        const float s_g2p = partials[(b * 2 + 1) * 2];      // gt2pred sum
        acc += s_p2g * (1.f / NPTS) + s_g2p * (1.f / NPTS) + m_p2g;
    }
    out[0] = acc * (1.f / BATCH);
}

extern "C" void kernel_launch(void* const* d_in, const int* in_sizes, int n_in,
                              void* d_out, int out_size, void* d_ws, size_t ws_size,
                              hipStream_t stream) {
    const float* pred = (const float*)d_in[0];
    const float* gt   = (const float*)d_in[1];
    float* out = (float*)d_out;

    float* pmin     = (float*)d_ws;                               // 2*B*SLICES*NPTS floats = 4 MB
    float* partials = pmin + (size_t)2 * BATCH * SLICES * NPTS;   // 16 floats

    dim3 g1(NCHUNKS, SLICES, 2 * BATCH);   // 4 x 16 x 8 = 512 blocks
    nn_partial<<<g1, TPB, 0, stream>>>(pred, gt, pmin);
    reduce_bd<<<dim3(2 * BATCH), 256, 0, stream>>>(pmin, partials);
    finalize<<<1, 1, 0, stream>>>(partials, out);
}

// Round 2
// 108.697 us; speedup vs baseline: 1.1425x; 1.1425x over previous
//
#include <hip/hip_runtime.h>

// ChamferLoss: B=4, N=M=8192, D=3, fp32.
// loss = mean_b[ mean(pred2gt) + mean(gt2pred) + max(pred2gt) ]
// d = ||x||^2 + ||y||^2 - 2 x.y with y pre-transformed to (-2y, ||y||^2) in LDS.
// R2: 1024 blocks (4 waves/SIMD, was 2 -> latency hiding), y-pair unroll with
// v_min3, wide 128-block reduction tail (was 8-block, ~59us of 124).

#define BATCH   4
#define NPTS    8192
#define SLICES  32
#define MS      (NPTS / SLICES)     // 256 y-points per slice
#define PPT     8                   // x-points per thread (register tile)
#define TPB     256
#define CHUNK   (TPB * PPT)         // 2048 x-points per block
#define NCHUNKS (NPTS / CHUNK)      // 4

__global__ __launch_bounds__(TPB)
void nn_partial(const float* __restrict__ pred,
                const float* __restrict__ gt,
                float* __restrict__ pmin) {
    const int c  = blockIdx.x;       // x chunk
    const int s  = blockIdx.y;       // y slice
    const int bd = blockIdx.z;       // b*2 + dir
    const int b  = bd >> 1;
    const int dir = bd & 1;
    const float* x = (dir ? gt : pred) + (size_t)b * NPTS * 3;
    const float* y = (dir ? pred : gt) + (size_t)b * NPTS * 3;

    __shared__ float4 ys[MS];        // {-2yx, -2yy, -2yz, y2}
    const int t = threadIdx.x;
    for (int j = t; j < MS; j += TPB) {
        const float yx = y[(s * MS + j) * 3 + 0];
        const float yy = y[(s * MS + j) * 3 + 1];
        const float yz = y[(s * MS + j) * 3 + 2];
        ys[j] = make_float4(-2.f * yx, -2.f * yy, -2.f * yz,
                            yx * yx + yy * yy + yz * yz);
    }
    __syncthreads();

    float xx[PPT], xy[PPT], xz[PPT], x2[PPT], mn[PPT];
    #pragma unroll
    for (int k = 0; k < PPT; ++k) {
        const int p = c * CHUNK + k * TPB + t;
        xx[k] = x[p * 3 + 0];
        xy[k] = x[p * 3 + 1];
        xz[k] = x[p * 3 + 2];
        x2[k] = xx[k] * xx[k] + xy[k] * xy[k] + xz[k] * xz[k];
        mn[k] = 3.4e38f;
    }

    // y-pair unroll: 2 independent LDS loads in flight per iter; min3 on the
    // combine (2 add + 6 fma + 1 min3 per 2 pairs per point = 4.5 ops/pair).
    #pragma unroll 2
    for (int j = 0; j < MS; j += 2) {
        const float4 q0 = ys[j];
        const float4 q1 = ys[j + 1];
        #pragma unroll
        for (int k = 0; k < PPT; ++k) {
            float d0 = x2[k] + q0.w;
            d0 = fmaf(xz[k], q0.z, d0);
            d0 = fmaf(xy[k], q0.y, d0);
            d0 = fmaf(xx[k], q0.x, d0);
            float d1 = x2[k] + q1.w;
            d1 = fmaf(xz[k], q1.z, d1);
            d1 = fmaf(xy[k], q1.y, d1);
            d1 = fmaf(xx[k], q1.x, d1);
            mn[k] = fminf(mn[k], fminf(d0, d1));   // -> v_min3_f32
        }
    }

    float* o = pmin + ((size_t)bd * SLICES + s) * NPTS + c * CHUNK;
    #pragma unroll
    for (int k = 0; k < PPT; ++k) o[k * TPB + t] = mn[k];
}

// Stage 1: 128 blocks; block (bd,g) owns 512 points: min over SLICES partials,
// then block-level sum+max -> partials[(bd*16+g)*2 .. +1].
__global__ __launch_bounds__(256)
void reduce1(const float* __restrict__ pmin, float* __restrict__ partials) {
    const int bd = blockIdx.x >> 4;
    const int g  = blockIdx.x & 15;
    const int t  = threadIdx.x;
    const float* base = pmin + (size_t)bd * SLICES * NPTS;
    float sum = 0.f, mx = -1.f;
    #pragma unroll
    for (int i = 0; i < 2; ++i) {
        const int p = g * 512 + i * 256 + t;
        float m = 3.4e38f;
        #pragma unroll
        for (int s = 0; s < SLICES; ++s) m = fminf(m, base[s * NPTS + p]);
        sum += m;
        mx = fmaxf(mx, m);
    }
    __shared__ float ssum[4], smax[4];
    #pragma unroll
    for (int off = 32; off; off >>= 1) {
        sum += __shfl_down(sum, off, 64);
        mx = fmaxf(mx, __shfl_down(mx, off, 64));
    }
    const int w = t >> 6;
    if ((t & 63) == 0) { ssum[w] = sum; smax[w] = mx; }
    __syncthreads();
    if (t == 0) {
        partials[blockIdx.x * 2]     = ssum[0] + ssum[1] + ssum[2] + ssum[3];
        partials[blockIdx.x * 2 + 1] = fmaxf(fmaxf(smax[0], smax[1]),
                                             fmaxf(smax[2], smax[3]));
    }
}

// Stage 2: one 128-thread block; lane t owns (bd = t>>4, g = t&15).
__global__ __launch_bounds__(128)
void finalize(const float* __restrict__ partials, float* __restrict__ out) {
    const int t = threadIdx.x;
    float s = partials[t * 2];
    float m = partials[t * 2 + 1];
    #pragma unroll
    for (int off = 8; off; off >>= 1) {
        s += __shfl_down(s, off, 16);
        m = fmaxf(m, __shfl_down(m, off, 16));
    }
    __shared__ float S[8], M[8];
    if ((t & 15) == 0) { S[t >> 4] = s; M[t >> 4] = m; }
    __syncthreads();
    if (t == 0) {
        float acc = 0.f;
        #pragma unroll
        for (int b = 0; b < BATCH; ++b) {
            // bd=2b: pred2gt (sum+max), bd=2b+1: gt2pred (sum only)
            acc += S[2 * b] * (1.f / NPTS) + S[2 * b + 1] * (1.f / NPTS) + M[2 * b];
        }
        out[0] = acc * (1.f / BATCH);
    }
}

extern "C" void kernel_launch(void* const* d_in, const int* in_sizes, int n_in,
                              void* d_out, int out_size, void* d_ws, size_t ws_size,
                              hipStream_t stream) {
    const float* pred = (const float*)d_in[0];
    const float* gt   = (const float*)d_in[1];
    float* out = (float*)d_out;

    float* pmin     = (float*)d_ws;                               // 2*B*SLICES*NPTS floats = 8 MB
    float* partials = pmin + (size_t)2 * BATCH * SLICES * NPTS;   // 256 floats

    dim3 g1(NCHUNKS, SLICES, 2 * BATCH);   // 4 x 32 x 8 = 1024 blocks
    nn_partial<<<g1, TPB, 0, stream>>>(pred, gt, pmin);
    reduce1<<<dim3(2 * BATCH * 16), 256, 0, stream>>>(pmin, partials);
    finalize<<<1, 128, 0, stream>>>(partials, out);
}

// Round 3
// 98.450 us; speedup vs baseline: 1.2614x; 1.1041x over previous
//
#include <hip/hip_runtime.h>

// ChamferLoss: B=4, N=M=8192, D=3, fp32.
// loss = mean_b[ mean(pred2gt) + mean(gt2pred) + max(pred2gt) ]
// R3: (a) hoist x2 out of inner loop: track emin = min_j(y2_j - 2 x.y_j),
//     final d = x2 + emin  -> 3.5 VALU ops/pair (floor 24us).
//     (b) 2048 blocks = 8 waves/SIMD (max occupancy, VGPR ~56).
//     (c) fuse slice-reduce via uint-mapped atomicMin (sqdist >= 0 so float
//     order == uint order on bit patterns); 0xFF-memset init. 2 kernels total.

#define BATCH   4
#define NPTS    8192
#define SLICES  64
#define MS      (NPTS / SLICES)     // 128 y-points per slice
#define PPT     8                   // x-points per thread (register tile)
#define TPB     256
#define CHUNK   (TPB * PPT)         // 2048 x-points per block
#define NCHUNKS (NPTS / CHUNK)      // 4

__global__ __launch_bounds__(TPB)
void nn_fused(const float* __restrict__ pred,
              const float* __restrict__ gt,
              unsigned int* __restrict__ pmin) {
    const int c  = blockIdx.x;       // x chunk
    const int s  = blockIdx.y;       // y slice
    const int bd = blockIdx.z;       // b*2 + dir
    const int b  = bd >> 1;
    const int dir = bd & 1;
    const float* x = (dir ? gt : pred) + (size_t)b * NPTS * 3;
    const float* y = (dir ? pred : gt) + (size_t)b * NPTS * 3;

    __shared__ float4 ys[MS];        // {yx, yy, yz, y2}
    const int t = threadIdx.x;
    if (t < MS) {
        const float yx = y[(s * MS + t) * 3 + 0];
        const float yy = y[(s * MS + t) * 3 + 1];
        const float yz = y[(s * MS + t) * 3 + 2];
        ys[t] = make_float4(yx, yy, yz, yx * yx + yy * yy + yz * yz);
    }
    __syncthreads();

    // px = -2x so that e_j = y2 + px.y ; d_j = x2 + e_j ; min hoists x2 out.
    float px[PPT], py[PPT], pz[PPT], x2[PPT], emin[PPT];
    #pragma unroll
    for (int k = 0; k < PPT; ++k) {
        const int p = c * CHUNK + k * TPB + t;
        const float xx = x[p * 3 + 0];
        const float xy = x[p * 3 + 1];
        const float xz = x[p * 3 + 2];
        x2[k] = xx * xx + xy * xy + xz * xz;
        px[k] = -2.f * xx;
        py[k] = -2.f * xy;
        pz[k] = -2.f * xz;
        emin[k] = 3.4e38f;
    }

    // 7 ops per point per 2 y (6 fma + 1 min3) = 3.5 ops/pair.
    #pragma unroll 2
    for (int j = 0; j < MS; j += 2) {
        const float4 q0 = ys[j];
        const float4 q1 = ys[j + 1];
        #pragma unroll
        for (int k = 0; k < PPT; ++k) {
            float e0 = fmaf(pz[k], q0.z, fmaf(py[k], q0.y, fmaf(px[k], q0.x, q0.w)));
            float e1 = fmaf(pz[k], q1.z, fmaf(py[k], q1.y, fmaf(px[k], q1.x, q1.w)));
            emin[k] = fminf(emin[k], fminf(e0, e1));   // -> v_min3_f32
        }
    }

    unsigned int* o = pmin + (size_t)bd * NPTS + c * CHUNK;
    #pragma unroll
    for (int k = 0; k < PPT; ++k) {
        const float d = fmaxf(emin[k] + x2[k], 0.f);   // sqdist >= 0
        atomicMin(&o[k * TPB + t], __float_as_uint(d));
    }
}

// 8 blocks, one per (b,dir): sum + max of 8192 mins, atomicAdd contribution.
__global__ __launch_bounds__(256)
void reduce_final(const unsigned int* __restrict__ pmin,
                  float* __restrict__ out) {
    const int bd = blockIdx.x;
    const int t  = threadIdx.x;
    const unsigned int* base = pmin + (size_t)bd * NPTS;
    float sum = 0.f, mx = -1.f;
    #pragma unroll
    for (int i = 0; i < NPTS / 256; ++i) {
        const float f = __uint_as_float(base[i * 256 + t]);
        sum += f;
        mx = fmaxf(mx, f);
    }
    __shared__ float ssum[4], smax[4];
    #pragma unroll
    for (int off = 32; off; off >>= 1) {
        sum += __shfl_down(sum, off, 64);
        mx = fmaxf(mx, __shfl_down(mx, off, 64));
    }
    const int w = t >> 6;
    if ((t & 63) == 0) { ssum[w] = sum; smax[w] = mx; }
    __syncthreads();
    if (t == 0) {
        const float S = ssum[0] + ssum[1] + ssum[2] + ssum[3];
        const float M = fmaxf(fmaxf(smax[0], smax[1]), fmaxf(smax[2], smax[3]));
        // bd even (pred2gt): mean + max ; bd odd (gt2pred): mean only.
        const float contrib = (S * (1.f / NPTS) + ((bd & 1) ? 0.f : M)) * (1.f / BATCH);
        atomicAdd(out, contrib);
    }
}

extern "C" void kernel_launch(void* const* d_in, const int* in_sizes, int n_in,
                              void* d_out, int out_size, void* d_ws, size_t ws_size,
                              hipStream_t stream) {
    const float* pred = (const float*)d_in[0];
    const float* gt   = (const float*)d_in[1];

    unsigned int* pmin = (unsigned int*)d_ws;   // 2*B*NPTS uints = 256 KB

    hipMemsetAsync(d_out, 0, sizeof(float), stream);                       // atomicAdd init
    hipMemsetAsync(pmin, 0xFF, (size_t)2 * BATCH * NPTS * 4, stream);      // +inf for uint-min

    dim3 g1(NCHUNKS, SLICES, 2 * BATCH);   // 4 x 64 x 8 = 2048 blocks
    nn_fused<<<g1, TPB, 0, stream>>>(pred, gt, pmin);
    reduce_final<<<dim3(2 * BATCH), 256, 0, stream>>>(pmin, (float*)d_out);
}